// Round 5
// baseline (455.830 us; speedup 1.0000x reference)
//
#include <hip/hip_runtime.h>

// Problem constants
#define Bsz 16
#define Dch 1024
#define Tsz 1024
#define Hsz 1024
#define Mtot (Bsz*Tsz)   // 16384
#define K2   (2*Dch)     // 2048
#define Ntot (3*Hsz)     // 3072
#define NCH  32          // scan chunks per chain
#define CL   32          // chunk length (NCH*CL == Tsz)
#define NT   32          // K-tiles in GEMM (K2/64)

typedef __attribute__((ext_vector_type(8))) short bf16x8;
typedef __attribute__((ext_vector_type(4))) float f32x4;

__device__ __forceinline__ unsigned short f2bf(float x) {
    unsigned u = __float_as_uint(x);
    u += 0x7FFFu + ((u >> 16) & 1u);   // round-to-nearest-even
    return (unsigned short)(u >> 16);
}
__device__ __forceinline__ float bf2f(unsigned short s) {
    return __uint_as_float(((unsigned)s) << 16);
}

// async global->LDS, 16B per lane, dest = ldsbase + lane*16 (wave-uniform base)
#define GLOAD_LDS16(gp, lp) \
    __builtin_amdgcn_global_load_lds((const __attribute__((address_space(1))) void*)(gp), \
                                     (__attribute__((address_space(3))) void*)(lp), 16, 0, 0)

// generic LDS pointer -> 32-bit LDS byte offset (for inline-asm ds_read)
#define LDSB(p) ((unsigned)(unsigned long long)(__attribute__((address_space(3))) const void*)(p))

// inline-asm ds_read_b128 (invisible to SIInsertWaitcnts; arrival enforced by
// our counted lgkmcnt + sched_barrier per rule #18)
#define DSR(dst, addr, off) \
    asm volatile("ds_read_b128 %0, %1 offset:" #off : "=v"(dst) : "v"(addr))

// counted lgkmcnt wait + scheduling fence
#define WAITLG(n) do { \
    asm volatile("s_waitcnt lgkmcnt(" #n ")" ::: "memory"); \
    __builtin_amdgcn_sched_barrier(0); } while (0)

// counted vmcnt wait + scheduling fence
#define VMC(n) do { \
    asm volatile("s_waitcnt vmcnt(" #n ")" ::: "memory"); \
    __builtin_amdgcn_sched_barrier(0); } while (0)

#define BAR __builtin_amdgcn_s_barrier()

// Merged prep: blocks [0,4096) build A2 (LDS transpose + causal shift + bf16 pack);
// blocks [4096,5632) cast conv_w fp32->bf16 (flat layout IS B^T row-major already).
__global__ __launch_bounds__(256)
void prep(const float* __restrict__ x, unsigned short* __restrict__ a2,
          const float* __restrict__ w, unsigned short* __restrict__ wb) {
    __shared__ float Xs[64][66];
    int bid = blockIdx.x;
    int tid = threadIdx.x;
    if (bid >= 4096) {
        int i0 = (bid - 4096) * 256 + tid;
        #pragma unroll
        for (int k = 0; k < 4; k++) {
            int i = i0 + k * (1536 * 256);
            float4 v = ((const float4*)w)[i];
            ushort4 r;
            r.x = f2bf(v.x); r.y = f2bf(v.y); r.z = f2bf(v.z); r.w = f2bf(v.w);
            ((ushort4*)wb)[i] = r;
        }
        return;
    }
    int b   = bid >> 8;
    int tt0 = ((bid >> 4) & 15) << 6;
    int dd0 = (bid & 15) << 6;
    int colt = tid & 63, rowq = tid >> 6;
    const size_t xbase = (size_t)b * (Dch * Tsz);
    #pragma unroll
    for (int r = 0; r < 16; r++) {
        int dd = r * 4 + rowq;
        Xs[dd][1 + colt] = x[xbase + (size_t)(dd0 + dd) * Tsz + tt0 + colt];
    }
    if (tid < 64) {
        Xs[tid][0] = (tt0 == 0) ? 0.f : x[xbase + (size_t)(dd0 + tid) * Tsz + tt0 - 1];
    }
    __syncthreads();
    #pragma unroll
    for (int r = 0; r < 16; r++) {
        int tr = r * 4 + rowq;
        int dc = colt;
        float v0 = Xs[dc][tr];       // x[t-1]
        float v1 = Xs[dc][tr + 1];   // x[t]
        unsigned pack = (unsigned)f2bf(v0) | ((unsigned)f2bf(v1) << 16);
        int m = (b << 10) + tt0 + tr;
        ((unsigned*)a2)[(size_t)m * (K2 / 2) + dd0 + dc] = pack;
    }
}

// ===========================================================================
// 256x256-tile, BK=64, 8-wave (2Mx4N), ONE-BARRIER-PER-TILE pipeline.
//
// R5 change: barriers cut 8 -> 1 per K-tile. R4 evidence: tile = 5363 cyc with
// MFMA 44%, DS ~53%, VALU 30% -- nothing saturated => sync-slop bound (8
// re-convergences/tile). The only CROSS-WAVE hazards are (a) publish "tile
// t+1 landed in LDS" and (b) WAR on buf[t&1] before staging t+2. One barrier
// carries both, PROVIDED every wave lgkm-proves all its tile-t reads before
// the barrier:
//   ph0: rd af23(t);            WAITLG(4)  [proves af01(t)+all B(t)]; MFMA p0
//   ph1: rd af45(t);            WAITLG(4)  [proves af23];             MFMA p1
//   ph2: rd af67(t);            WAITLG(0)  [proves af45 AND af67 -- the WAR
//        proof: ALL reads of buf[t&1]/bufB[t&1] now done pre-barrier]; MFMA p2
//        VMC(0) [drains the 8 staging loads issued 1 tile ago -- ~3300 cyc >>
//        900 cyc HBM latency, free]; BAR  == publish(t+1) + WAR-release(t&1)
//   ph3: rd af01(t+1) + all B(t+1) (12, from published buf[(t+1)&1]);
//        stage A(t+2)+B(t+2) -> buf[t&1] (post-BAR, WAR-safe for ALL waves);
//        WAITLG(12) [af67 already proven; pure fence]; MFMA p3
// Waves flow freely ph3->ph0->ph1->ph2 (max slip = 1 barrier). lgkm enters
// every tile at exactly 12 (af01' 4 + B' 8); vmcnt holds only the 8 stages.
// B fragments per-tile-parity sets bfrE/bfrO; A pairs ping-pong afA/afB.
// ===========================================================================
#define MF(slot, bset, p) do { \
    _Pragma("unroll") for (int ks_ = 0; ks_ < 2; ++ks_) { \
      _Pragma("unroll") for (int d_ = 0; d_ < 2; ++d_) { \
        _Pragma("unroll") for (int j_ = 0; j_ < 4; ++j_) { \
          acc[2*(p)+d_][j_] = __builtin_amdgcn_mfma_f32_16x16x32_bf16( \
              slot[d_][ks_], bset[ks_][j_], acc[2*(p)+d_][j_], 0, 0, 0); \
        } } } } while (0)

__global__ __launch_bounds__(512, 2)
void gemm_gates(const unsigned short* __restrict__ A, const unsigned short* __restrict__ Bt,
                const float* __restrict__ bias,
                float* __restrict__ zc, float* __restrict__ fh, unsigned short* __restrict__ ob) {
    __shared__ __align__(16) unsigned short As[2][16384];
    __shared__ __align__(16) unsigned short Bs[2][16384];

    int tid  = threadIdx.x;
    int wv   = tid >> 6, lane = tid & 63;
    int wm   = wv >> 2, wn = wv & 3;        // 2 x 4 waves -> 128x64 per wave
    int lm   = lane & 15, q = lane >> 4;

    // XCD-aware bijective swizzle: 768 wgs = 8 XCDs x 96
    int bid = blockIdx.x;
    int swz = (bid & 7) * 96 + (bid >> 3);
    int mt = swz / 12, nt = swz % 12;       // 64 m-tiles x 12 n-tiles
    int m0 = mt << 8, n0 = nt << 8;

    const unsigned short* Abase = A  + (size_t)m0 * K2;
    const unsigned short* Bbase = Bt + (size_t)n0 * K2;

    // staging: lane covers row (wv*8 + l>>3), chunk (l&7); global chunk
    // pre-swizzled by ^(row&7) = ^(l>>3); LDS dest linear.
    int loff   = (wv * 8 + (lane >> 3)) * K2 + (((lane & 7) ^ (lane >> 3)) << 3);
    int ldsoff = wv * 8 * 64;

    // fragment-read constants (ushort units)
    int sw  = lm & 7;
    int kc0 = (q ^ sw) << 3;          // k-slice 0 -> chunks 0..3
    int kc1 = ((4 + q) ^ sw) << 3;    // k-slice 1 -> chunks 4..7
    int aoff = (wm * 128 + lm) * 64;
    int boff = (wn * 64 + lm) * 64;

    unsigned asb = LDSB(&As[0][0]);
    unsigned bsb = LDSB(&Bs[0][0]);
    unsigned aA0 = asb + (unsigned)(aoff + kc0) * 2u;
    unsigned aA1 = asb + (unsigned)(aoff + kc1) * 2u;
    unsigned aB0 = bsb + (unsigned)(boff + kc0) * 2u;
    unsigned aB1 = bsb + (unsigned)(boff + kc1) * 2u;

    f32x4 acc[8][4] = {};
    bf16x8 afA[2][2], afB[2][2];      // ping-pong A-pair slots [d][kslice]
    bf16x8 bfrE[2][4], bfrO[2][4];    // per-tile-parity B sets [kslice][j]

#define STAGE_A(t, h) do { \
    const unsigned short* g_ = Abase + (h) * (128 * K2) + (t) * 64 + loff; \
    unsigned short* l_ = &As[(t) & 1][(h) * 8192 + ldsoff]; \
    GLOAD_LDS16(g_, l_); \
    GLOAD_LDS16(g_ + 64 * K2, l_ + 64 * 64); } while (0)
#define STAGE_B(t, h) do { \
    const unsigned short* g_ = Bbase + (h) * (128 * K2) + (t) * 64 + loff; \
    unsigned short* l_ = &Bs[(t) & 1][(h) * 8192 + ldsoff]; \
    GLOAD_LDS16(g_, l_); \
    GLOAD_LDS16(g_ + 64 * K2, l_ + 64 * 64); } while (0)

// A-pair read: pair at byte offsets o0/o1 (rows 2p, 2p+1), both k-slices
#define R_AFP(slot, o0, o1, bo) do { \
    DSR(slot[0][0], aA0 + (bo), o0); DSR(slot[0][1], aA1 + (bo), o0); \
    DSR(slot[1][0], aA0 + (bo), o1); DSR(slot[1][1], aA1 + (bo), o1); } while (0)
// B half-reads (j=0,1 / j=2,3), both k-slices
#define R_BH0(set, bo) do { \
    DSR(set[0][0], aB0 + (bo), 0);    DSR(set[1][0], aB1 + (bo), 0); \
    DSR(set[0][1], aB0 + (bo), 2048); DSR(set[1][1], aB1 + (bo), 2048); } while (0)
#define R_BH1(set, bo) do { \
    DSR(set[0][2], aB0 + (bo), 4096); DSR(set[1][2], aB1 + (bo), 4096); \
    DSR(set[0][3], aB0 + (bo), 6144); DSR(set[1][3], aB1 + (bo), 6144); } while (0)

#define PRIO1 __builtin_amdgcn_s_setprio(1)
#define PRIO0 do { __builtin_amdgcn_s_setprio(0); __builtin_amdgcn_sched_barrier(0); } while (0)

// Phases 0-2 of tile with buffer offset CB, consuming B-set BC.
// Single barrier at close of ph2 (publish + WAR-release).
#define PH012(CB, BC) do { \
    R_AFP(afB, 4096, 6144, CB); \
    WAITLG(4); \
    PRIO1; MF(afA, BC, 0); PRIO0; \
    R_AFP(afA, 8192, 10240, CB); \
    WAITLG(4); \
    PRIO1; MF(afB, BC, 1); PRIO0; \
    R_AFP(afB, 12288, 14336, CB); \
    WAITLG(0); \
    PRIO1; MF(afA, BC, 2); PRIO0; \
    VMC(0); \
    BAR; } while (0)

// Phase 3: read next tile's af01+B into (afA, BN) from buf offset NB;
// stage tile T+2; finish MFMA p3 with current B-set BC.
#define PH3(T, NB, BC, BN) do { \
    R_AFP(afA, 0, 2048, NB); \
    R_BH0(BN, NB); R_BH1(BN, NB); \
    STAGE_A((T) + 2, 0); STAGE_A((T) + 2, 1); \
    STAGE_B((T) + 2, 0); STAGE_B((T) + 2, 1); \
    WAITLG(12); \
    PRIO1; MF(afB, BC, 3); PRIO0; } while (0)

#define PH3_NOSTAGE(NB, BC, BN) do { \
    R_AFP(afA, 0, 2048, NB); \
    R_BH0(BN, NB); R_BH1(BN, NB); \
    WAITLG(12); \
    PRIO1; MF(afB, BC, 3); PRIO0; } while (0)

#define PH3_LAST(BC) do { \
    WAITLG(0); \
    PRIO1; MF(afB, BC, 3); PRIO0; } while (0)

    // ---- Prologue: tile0 staged+published; read af01(0)+B(0); stage tile1.
    STAGE_A(0, 0); STAGE_A(0, 1); STAGE_B(0, 0); STAGE_B(0, 1);
    VMC(0); BAR;                       // tile0 in LDS
    R_AFP(afA, 0, 2048, 0u);
    R_BH0(bfrE, 0u); R_BH1(bfrE, 0u); // B(0) -> E   (lgkm = 12)
    STAGE_A(1, 0); STAGE_A(1, 1); STAGE_B(1, 0); STAGE_B(1, 1);  // vmem = 8
    __builtin_amdgcn_sched_barrier(0);

    #pragma unroll 1
    for (int tp = 0; tp < 15; ++tp) {
        int t0 = 2 * tp;
        // even tile: cur=buf0, consume E; ph3 reads tile t0+1 from buf1 -> O
        PH012(0u, bfrE);
        PH3(t0, 32768u, bfrE, bfrO);
        // odd tile
        PH012(32768u, bfrO);
        PH3(t0 + 1, 0u, bfrO, bfrE);
    }
    // ---- t=30 (even): no stage of t+2=32
    PH012(0u, bfrE);
    PH3_NOSTAGE(32768u, bfrE, bfrO);
    // ---- t=31 (odd): final tile
    PH012(32768u, bfrO);
    PH3_LAST(bfrO);

    // Epilogue: C/D layout col=lane&15, row=(lane>>4)*4+reg.
    int gt = nt >> 2;   // 0:z(tanh) 1:f(sigm) 2:o(sigm->bf16)
    #pragma unroll
    for (int i = 0; i < 8; ++i) {
        int mrow = m0 + wm * 128 + i * 16 + q * 4;
        #pragma unroll
        for (int j = 0; j < 4; ++j) {
            int n = n0 + wn * 64 + j * 16 + lm;
            float bv = bias[n];
            int hcol = n & 1023;
            #pragma unroll
            for (int r = 0; r < 4; ++r) {
                float g = acc[i][j][r] + bv;
                size_t idx = (size_t)(mrow + r) * Hsz + hcol;
                if (gt == 0) {
                    float e = __expf(2.f * g);
                    zc[idx] = __fdividef(e - 1.f, e + 1.f);
                } else {
                    float s = __fdividef(1.f, 1.f + __expf(-g));
                    if (gt == 1) fh[idx] = s;
                    else         ob[idx] = f2bf(s);
                }
            }
        }
    }
}

// ---- chunked fo-pooling scan: c_t = z + f*(c - z), c_0 = 0 ----
// NCH=32 chunks of CL=32 -> 1024 blocks.
__global__ __launch_bounds__(256)
void scan1(const float* __restrict__ zc, const float* __restrict__ fh,
           float* __restrict__ Aw, float* __restrict__ Bw) {
    int blk = blockIdx.x;                 // 16 b * 32 ch * 2 hb = 1024
    int hb = blk & 1, ch = (blk >> 1) & 31, b = blk >> 6;
    int h = hb * 512 + threadIdx.x * 2;
    size_t base = ((size_t)b << 20) + ((size_t)(ch * CL) << 10) + h;
    float ax = 1.f, ay = 1.f, bx = 0.f, by = 0.f;
    #pragma unroll 8
    for (int s = 0; s < CL; s++) {
        size_t idx = base + ((size_t)s << 10);
        float2 z = *(const float2*)&zc[idx];
        float2 f = *(const float2*)&fh[idx];
        ax *= f.x; ay *= f.y;
        bx = z.x + f.x * (bx - z.x);
        by = z.y + f.y * (by - z.y);
    }
    int o = (ch * Bsz + b) * Hsz + h;
    *(float2*)&Aw[o] = make_float2(ax, ay);
    *(float2*)&Bw[o] = make_float2(bx, by);
}

__global__ __launch_bounds__(256)
void scan3(float* __restrict__ zc, float* __restrict__ fh,
           const unsigned short* __restrict__ ob,
           const float* __restrict__ Aw, const float* __restrict__ Bw) {
    int blk = blockIdx.x;                 // 1024
    int hb = blk & 1, ch = (blk >> 1) & 31, b = blk >> 6;
    int h = hb * 512 + threadIdx.x * 2;
    float cx = 0.f, cy = 0.f;
    for (int cp = 0; cp < ch; cp++) {     // chunk-entry state (block-uniform trip)
        int o = (cp * Bsz + b) * Hsz + h;
        float2 A = *(const float2*)&Aw[o];
        float2 B = *(const float2*)&Bw[o];
        cx = A.x * cx + B.x;
        cy = A.y * cy + B.y;
    }
    size_t base = ((size_t)b << 20) + ((size_t)(ch * CL) << 10) + h;
    #pragma unroll 8
    for (int s = 0; s < CL; s++) {
        size_t idx = base + ((size_t)s << 10);
        float2 z = *(const float2*)&zc[idx];
        float2 f = *(const float2*)&fh[idx];
        unsigned ov = *(const unsigned*)&ob[idx];   // two bf16 o-gates
        cx = z.x + f.x * (cx - z.x);
        cy = z.y + f.y * (cy - z.y);
        *(float2*)&zc[idx] = make_float2(cx, cy);
        float ox = bf2f((unsigned short)(ov & 0xFFFF));
        float oy = bf2f((unsigned short)(ov >> 16));
        *(float2*)&fh[idx] = make_float2(ox * cx, oy * cy);
    }
}

extern "C" void kernel_launch(void* const* d_in, const int* in_sizes, int n_in,
                              void* d_out, int out_size, void* d_ws, size_t ws_size,
                              hipStream_t stream) {
    const float* x    = (const float*)d_in[0];   // [16,1024,1024]
    const float* w    = (const float*)d_in[1];   // [3072,1024,2]
    const float* bias = (const float*)d_in[2];   // [3072]
    float* zc = (float*)d_out;                               // c_seq out (holds z pre-scan)
    float* fh = (float*)d_out + (size_t)Mtot * Hsz;          // h_seq out (holds f pre-scan)
    unsigned short* a2 = (unsigned short*)d_ws;              // 64 MB
    unsigned short* wb = a2 + (size_t)Mtot * K2;             // 12.6 MB
    unsigned short* ob = wb + (size_t)Ntot * K2;             // 32 MB (o gate, bf16)
    float* Aw = (float*)(ob + (size_t)Mtot * Hsz);           // 2 MB
    float* Bw = Aw + NCH * Bsz * Hsz;                        // 2 MB

    hipLaunchKernelGGL(prep, dim3(5632), dim3(256), 0, stream, x, a2, w, wb);
    hipLaunchKernelGGL(gemm_gates, dim3(768), dim3(512), 0, stream, a2, wb, bias, zc, fh, ob);
    hipLaunchKernelGGL(scan1, dim3(1024), dim3(256), 0, stream, zc, fh, Aw, Bw);
    hipLaunchKernelGGL(scan3, dim3(1024), dim3(256), 0, stream, zc, fh, ob, Aw, Bw);
}

// Round 7
// 448.671 us; speedup vs baseline: 1.0160x; 1.0160x over previous
//
#include <hip/hip_runtime.h>

// Problem constants
#define Bsz 16
#define Dch 1024
#define Tsz 1024
#define Hsz 1024
#define Mtot (Bsz*Tsz)   // 16384
#define K2   (2*Dch)     // 2048
#define Ntot (3*Hsz)     // 3072
#define NCH  32          // scan chunks per chain
#define CL   32          // chunk length (NCH*CL == Tsz)
#define NT   32          // K-tiles in GEMM (K2/64)

typedef __attribute__((ext_vector_type(8))) short bf16x8;
typedef __attribute__((ext_vector_type(4))) float f32x4;

__device__ __forceinline__ unsigned short f2bf(float x) {
    unsigned u = __float_as_uint(x);
    u += 0x7FFFu + ((u >> 16) & 1u);   // round-to-nearest-even
    return (unsigned short)(u >> 16);
}
__device__ __forceinline__ float bf2f(unsigned short s) {
    return __uint_as_float(((unsigned)s) << 16);
}

// async global->LDS, 16B per lane, dest = ldsbase + lane*16 (wave-uniform base)
#define GLOAD_LDS16(gp, lp) \
    __builtin_amdgcn_global_load_lds((const __attribute__((address_space(1))) void*)(gp), \
                                     (__attribute__((address_space(3))) void*)(lp), 16, 0, 0)

// generic LDS pointer -> 32-bit LDS byte offset (for inline-asm ds_read)
#define LDSB(p) ((unsigned)(unsigned long long)(__attribute__((address_space(3))) const void*)(p))

// inline-asm ds_read_b128 (invisible to SIInsertWaitcnts; arrival enforced by
// our counted lgkmcnt + sched_barrier per rule #18)
#define DSR(dst, addr, off) \
    asm volatile("ds_read_b128 %0, %1 offset:" #off : "=v"(dst) : "v"(addr))

// counted lgkmcnt wait + scheduling fence
#define WAITLG(n) do { \
    asm volatile("s_waitcnt lgkmcnt(" #n ")" ::: "memory"); \
    __builtin_amdgcn_sched_barrier(0); } while (0)

// counted vmcnt wait + scheduling fence
#define VMC(n) do { \
    asm volatile("s_waitcnt vmcnt(" #n ")" ::: "memory"); \
    __builtin_amdgcn_sched_barrier(0); } while (0)

#define BAR __builtin_amdgcn_s_barrier()

// ===========================================================================
// prep (R7 rewrite): 256-wide t-tiles for 4x read coalescing.
// Blocks [0,1024): A2 build. b(16) x tt(4, 256 t each) x dd(16, 64 d each).
//   Load: float4 along t -> one wave covers a full 1KB row of x. LDS
//   Xs[64][257] (odd stride: write-phase reads land exactly 2-way banked =
//   free). Causal shift via Xprev[64] column (x[tt0-1]) -- no offset games.
//   Write: each thread packs 4 consecutive d -> uint4 (16B/lane).
// Blocks [1024,2560): conv_w fp32->bf16 cast (float4 in, ushort4 out).
// ===========================================================================
__global__ __launch_bounds__(256)
void prep(const float* __restrict__ x, unsigned short* __restrict__ a2,
          const float* __restrict__ w, unsigned short* __restrict__ wb) {
    __shared__ float Xs[64 * 257];
    __shared__ float Xprev[64];
    int bid = blockIdx.x;
    int tid = threadIdx.x;
    if (bid >= 1024) {
        // prep_w: 1536 blocks * 256 thr * 4 float4
        int i0 = (bid - 1024) * 256 + tid;
        #pragma unroll
        for (int k = 0; k < 4; k++) {
            int i = i0 + k * (1536 * 256);
            float4 v = ((const float4*)w)[i];
            ushort4 r;
            r.x = f2bf(v.x); r.y = f2bf(v.y); r.z = f2bf(v.z); r.w = f2bf(v.w);
            ((ushort4*)wb)[i] = r;
        }
        return;
    }
    int b   = bid >> 6;
    int tt0 = ((bid >> 4) & 3) << 8;      // 256-wide t-tile
    int dd0 = (bid & 15) << 6;            // 64-wide d-tile
    const size_t xbase = (size_t)b * (Dch * Tsz);

    // load phase: wave w covers row dd = it*4 + (tid>>6), lanes cover 64 f4s
    int c4 = tid & 63, rq = tid >> 6;
    #pragma unroll
    for (int it = 0; it < 16; ++it) {
        int dd = it * 4 + rq;
        float4 v = *(const float4*)&x[xbase + (size_t)(dd0 + dd) * Tsz + tt0 + c4 * 4];
        float* p = &Xs[dd * 257 + c4 * 4];
        p[0] = v.x; p[1] = v.y; p[2] = v.z; p[3] = v.w;
    }
    if (tid < 64)
        Xprev[tid] = (tt0 == 0) ? 0.f : x[xbase + (size_t)(dd0 + tid) * Tsz + tt0 - 1];
    __syncthreads();

    // write phase: pass p covers 16 m-rows; thread packs 4 consecutive d
    int trq = tid >> 4, dcq = tid & 15;
    #pragma unroll
    for (int p = 0; p < 16; ++p) {
        int tr = p * 16 + trq;
        unsigned pk[4];
        #pragma unroll
        for (int k = 0; k < 4; ++k) {
            int dc = dcq * 4 + k;
            float v1 = Xs[dc * 257 + tr];
            float v0 = (tr == 0) ? Xprev[dc] : Xs[dc * 257 + tr - 1];
            pk[k] = (unsigned)f2bf(v0) | ((unsigned)f2bf(v1) << 16);
        }
        int m = (b << 10) + tt0 + tr;
        uint4 out; out.x = pk[0]; out.y = pk[1]; out.z = pk[2]; out.w = pk[3];
        *(uint4*)&((unsigned*)a2)[(size_t)m * 1024 + dd0 + dcq * 4] = out;
    }
}

// ===========================================================================
// GEMM: R4 variant (best measured: 214.5 us, MfmaUtil 43.5) — A-pair-clustered,
// split-publish pipeline, 4 barriers/tile. Unchanged.
// ===========================================================================
#define MF(slot, bset, p) do { \
    _Pragma("unroll") for (int ks_ = 0; ks_ < 2; ++ks_) { \
      _Pragma("unroll") for (int d_ = 0; d_ < 2; ++d_) { \
        _Pragma("unroll") for (int j_ = 0; j_ < 4; ++j_) { \
          acc[2*(p)+d_][j_] = __builtin_amdgcn_mfma_f32_16x16x32_bf16( \
              slot[d_][ks_], bset[ks_][j_], acc[2*(p)+d_][j_], 0, 0, 0); \
        } } } } while (0)

__global__ __launch_bounds__(512, 2)
void gemm_gates(const unsigned short* __restrict__ A, const unsigned short* __restrict__ Bt,
                const float* __restrict__ bias,
                float* __restrict__ zc, float* __restrict__ fh, unsigned short* __restrict__ ob) {
    __shared__ __align__(16) unsigned short As[2][16384];
    __shared__ __align__(16) unsigned short Bs[2][16384];

    int tid  = threadIdx.x;
    int wv   = tid >> 6, lane = tid & 63;
    int wm   = wv >> 2, wn = wv & 3;        // 2 x 4 waves -> 128x64 per wave
    int lm   = lane & 15, q = lane >> 4;

    // XCD-aware bijective swizzle: 768 wgs = 8 XCDs x 96
    int bid = blockIdx.x;
    int swz = (bid & 7) * 96 + (bid >> 3);
    int mt = swz / 12, nt = swz % 12;       // 64 m-tiles x 12 n-tiles
    int m0 = mt << 8, n0 = nt << 8;

    const unsigned short* Abase = A  + (size_t)m0 * K2;
    const unsigned short* Bbase = Bt + (size_t)n0 * K2;

    // staging: lane covers row (wv*8 + l>>3), chunk (l&7); global chunk
    // pre-swizzled by ^(row&7) = ^(l>>3); LDS dest linear.
    int loff   = (wv * 8 + (lane >> 3)) * K2 + (((lane & 7) ^ (lane >> 3)) << 3);
    int ldsoff = wv * 8 * 64;

    // fragment-read constants (ushort units)
    int sw  = lm & 7;
    int kc0 = (q ^ sw) << 3;          // k-slice 0 -> chunks 0..3
    int kc1 = ((4 + q) ^ sw) << 3;    // k-slice 1 -> chunks 4..7
    int aoff = (wm * 128 + lm) * 64;
    int boff = (wn * 64 + lm) * 64;

    unsigned asb = LDSB(&As[0][0]);
    unsigned bsb = LDSB(&Bs[0][0]);
    unsigned aA0 = asb + (unsigned)(aoff + kc0) * 2u;
    unsigned aA1 = asb + (unsigned)(aoff + kc1) * 2u;
    unsigned aB0 = bsb + (unsigned)(boff + kc0) * 2u;
    unsigned aB1 = bsb + (unsigned)(boff + kc1) * 2u;

    f32x4 acc[8][4] = {};
    bf16x8 afA[2][2], afB[2][2];      // ping-pong A-pair slots [d][kslice]
    bf16x8 bfrE[2][4], bfrO[2][4];    // per-tile-parity B sets [kslice][j]

#define STAGE_A(t, h) do { \
    const unsigned short* g_ = Abase + (h) * (128 * K2) + (t) * 64 + loff; \
    unsigned short* l_ = &As[(t) & 1][(h) * 8192 + ldsoff]; \
    GLOAD_LDS16(g_, l_); \
    GLOAD_LDS16(g_ + 64 * K2, l_ + 64 * 64); } while (0)
#define STAGE_B(t, h) do { \
    const unsigned short* g_ = Bbase + (h) * (128 * K2) + (t) * 64 + loff; \
    unsigned short* l_ = &Bs[(t) & 1][(h) * 8192 + ldsoff]; \
    GLOAD_LDS16(g_, l_); \
    GLOAD_LDS16(g_ + 64 * K2, l_ + 64 * 64); } while (0)

// A-pair read: pair at byte offsets o0/o1 (rows 2p, 2p+1), both k-slices
#define R_AFP(slot, o0, o1, bo) do { \
    DSR(slot[0][0], aA0 + (bo), o0); DSR(slot[0][1], aA1 + (bo), o0); \
    DSR(slot[1][0], aA0 + (bo), o1); DSR(slot[1][1], aA1 + (bo), o1); } while (0)
// B half-reads (j=0,1 / j=2,3), both k-slices
#define R_BH0(set, bo) do { \
    DSR(set[0][0], aB0 + (bo), 0);    DSR(set[1][0], aB1 + (bo), 0); \
    DSR(set[0][1], aB0 + (bo), 2048); DSR(set[1][1], aB1 + (bo), 2048); } while (0)
#define R_BH1(set, bo) do { \
    DSR(set[0][2], aB0 + (bo), 4096); DSR(set[1][2], aB1 + (bo), 4096); \
    DSR(set[0][3], aB0 + (bo), 6144); DSR(set[1][3], aB1 + (bo), 6144); } while (0)

#define PRIO1 __builtin_amdgcn_s_setprio(1)
#define PRIO0 do { __builtin_amdgcn_s_setprio(0); __builtin_amdgcn_sched_barrier(0); } while (0)

// Phase macros (steady-state). T is the current tile index (runtime).
#define PH0(T, CB, BC) do { \
    R_AFP(afB, 4096, 6144, CB); \
    STAGE_A((T) + 1, 1); \
    WAITLG(4); \
    PRIO1; MF(afA, BC, 0); PRIO0; } while (0)
#define PH1(T, CB, NB, BC, BN) do { \
    R_AFP(afA, 8192, 10240, CB); \
    R_BH0(BN, NB); \
    STAGE_A((T) + 1, 0); \
    WAITLG(8); \
    PRIO1; MF(afB, BC, 1); PRIO0; } while (0)
#define PH2(T, CB, NB, BC, BN) do { \
    R_AFP(afB, 12288, 14336, CB); \
    R_BH1(BN, NB); \
    STAGE_B((T) + 2, 1); \
    WAITLG(8); \
    PRIO1; MF(afA, BC, 2); PRIO0; } while (0)
#define PH3(T, NB, BC) do { \
    R_AFP(afA, 0, 2048, NB); \
    STAGE_B((T) + 2, 0); \
    WAITLG(4); \
    PRIO1; MF(afB, BC, 3); PRIO0; } while (0)

    // ---- Prologue: tile0 fully + B(1); read af01(0) + all bfrE(0).
    STAGE_A(0, 0); STAGE_A(0, 1); STAGE_B(0, 0); STAGE_B(0, 1);
    STAGE_B(1, 1); STAGE_B(1, 0);
    VMC(4); BAR;                       // tile0's 8 loads landed
    R_AFP(afA, 0, 2048, 0u);
    R_BH0(bfrE, 0u); R_BH1(bfrE, 0u);
    __builtin_amdgcn_sched_barrier(0);

    #pragma unroll 1
    for (int tp = 0; tp < 15; ++tp) {
        int t0 = 2 * tp;
        // even tile: cur=buf0, nxt=buf1, consume bfrE, fill bfrO
        PH0(t0, 0u, bfrE);                 VMC(2); BAR;   // proves B(t0+1)
        PH1(t0, 0u, 32768u, bfrE, bfrO);           BAR;
        PH2(t0, 0u, 32768u, bfrE, bfrO);   VMC(2); BAR;   // publish A(t0+1)
        PH3(t0, 32768u, bfrE);                     BAR;
        // odd tile
        PH0(t0 + 1, 32768u, bfrO);         VMC(2); BAR;
        PH1(t0 + 1, 32768u, 0u, bfrO, bfrE);       BAR;
        PH2(t0 + 1, 32768u, 0u, bfrO, bfrE); VMC(2); BAR;
        PH3(t0 + 1, 0u, bfrO);                     BAR;
    }

    // ---- peeled t=30 (even; stages of t+2=32 dropped; drain at close ph2)
    PH0(30, 0u, bfrE);                     VMC(2); BAR;
    PH1(30, 0u, 32768u, bfrE, bfrO);               BAR;
    R_AFP(afB, 12288, 14336, 0u);
    R_BH1(bfrO, 32768u);
    WAITLG(8);
    PRIO1; MF(afA, bfrE, 2); PRIO0;
    VMC(0); BAR;                                   // drain: A(31) landed
    R_AFP(afA, 0, 2048, 32768u);                   // af01(31)
    WAITLG(4);
    PRIO1; MF(afB, bfrE, 3); PRIO0;
    BAR;

    // ---- peeled t=31 (cur=buf1, consume bfrO; no stages, no vmcnt)
    R_AFP(afB, 4096, 6144, 32768u);
    WAITLG(4);
    PRIO1; MF(afA, bfrO, 0); PRIO0; BAR;
    R_AFP(afA, 8192, 10240, 32768u);
    WAITLG(4);
    PRIO1; MF(afB, bfrO, 1); PRIO0; BAR;
    R_AFP(afB, 12288, 14336, 32768u);
    WAITLG(4);
    PRIO1; MF(afA, bfrO, 2); PRIO0; BAR;
    WAITLG(0);
    PRIO1; MF(afB, bfrO, 3); PRIO0;

    // Epilogue: C/D layout col=lane&15, row=(lane>>4)*4+reg.
    int gt = nt >> 2;   // 0:z(tanh) 1:f(sigm) 2:o(sigm->bf16)
    #pragma unroll
    for (int i = 0; i < 8; ++i) {
        int mrow = m0 + wm * 128 + i * 16 + q * 4;
        #pragma unroll
        for (int j = 0; j < 4; ++j) {
            int n = n0 + wn * 64 + j * 16 + lm;
            float bv = bias[n];
            int hcol = n & 1023;
            #pragma unroll
            for (int r = 0; r < 4; ++r) {
                float g = acc[i][j][r] + bv;
                size_t idx = (size_t)(mrow + r) * Hsz + hcol;
                if (gt == 0) {
                    float e = __expf(2.f * g);
                    zc[idx] = __fdividef(e - 1.f, e + 1.f);
                } else {
                    float s = __fdividef(1.f, 1.f + __expf(-g));
                    if (gt == 1) fh[idx] = s;
                    else         ob[idx] = f2bf(s);
                }
            }
        }
    }
}

// ---- chunked fo-pooling scan (two-pass, deterministic), float4 lanes ----
// Pass 1: per-chunk affine (a = prod f, b = chunk result from c_in=0).
// 512 blocks (16 b x 32 ch) x 256 thr, 4 h/thread (16B/lane loads).
__global__ __launch_bounds__(256)
void scan1(const float* __restrict__ zc, const float* __restrict__ fh,
           float* __restrict__ Aw, float* __restrict__ Bw) {
    int blk = blockIdx.x;                 // 512
    int ch = blk & (NCH - 1), b = blk >> 5;
    int h  = threadIdx.x << 2;
    size_t base = ((size_t)b << 20) + ((size_t)(ch * CL) << 10) + h;
    float a0 = 1.f, a1 = 1.f, a2v = 1.f, a3 = 1.f;
    float b0 = 0.f, b1 = 0.f, b2 = 0.f, b3 = 0.f;
    #pragma unroll 4
    for (int s = 0; s < CL; ++s) {
        size_t idx = base + ((size_t)s << 10);
        float4 z = *(const float4*)&zc[idx];
        float4 f = *(const float4*)&fh[idx];
        a0 *= f.x; a1 *= f.y; a2v *= f.z; a3 *= f.w;
        b0 = z.x + f.x * (b0 - z.x);
        b1 = z.y + f.y * (b1 - z.y);
        b2 = z.z + f.z * (b2 - z.z);
        b3 = z.w + f.w * (b3 - z.w);
    }
    int o = (ch * Bsz + b) * Hsz + h;
    *(float4*)&Aw[o] = make_float4(a0, a1, a2v, a3);
    *(float4*)&Bw[o] = make_float4(b0, b1, b2, b3);
}

// Pass 2 (merged prefix + apply): block folds its predecessors' affines
// (block-uniform short loop, L2-hot), then applies the recurrence in place:
// zc: z -> c_seq, fh: f -> h_seq = o * c.
__global__ __launch_bounds__(256)
void scan3(float* __restrict__ zc, float* __restrict__ fh,
           const unsigned short* __restrict__ ob,
           const float* __restrict__ Aw, const float* __restrict__ Bw) {
    int blk = blockIdx.x;                 // 512
    int ch = blk & (NCH - 1), b = blk >> 5;
    int h  = threadIdx.x << 2;
    float c0 = 0.f, c1 = 0.f, c2 = 0.f, c3 = 0.f;
    for (int cp = 0; cp < ch; cp++) {     // chunk-entry state
        int o = (cp * Bsz + b) * Hsz + h;
        float4 A = *(const float4*)&Aw[o];
        float4 B = *(const float4*)&Bw[o];
        c0 = A.x * c0 + B.x;
        c1 = A.y * c1 + B.y;
        c2 = A.z * c2 + B.z;
        c3 = A.w * c3 + B.w;
    }
    size_t base = ((size_t)b << 20) + ((size_t)(ch * CL) << 10) + h;
    #pragma unroll 4
    for (int s = 0; s < CL; ++s) {
        size_t idx = base + ((size_t)s << 10);
        float4 z = *(const float4*)&zc[idx];
        float4 f = *(const float4*)&fh[idx];
        uint2 ov = *(const uint2*)&ob[idx];
        c0 = z.x + f.x * (c0 - z.x);
        c1 = z.y + f.y * (c1 - z.y);
        c2 = z.z + f.z * (c2 - z.z);
        c3 = z.w + f.w * (c3 - z.w);
        *(float4*)&zc[idx] = make_float4(c0, c1, c2, c3);
        float o0 = bf2f((unsigned short)(ov.x & 0xFFFF));
        float o1 = bf2f((unsigned short)(ov.x >> 16));
        float o2 = bf2f((unsigned short)(ov.y & 0xFFFF));
        float o3 = bf2f((unsigned short)(ov.y >> 16));
        *(float4*)&fh[idx] = make_float4(o0 * c0, o1 * c1, o2 * c2, o3 * c3);
    }
}

extern "C" void kernel_launch(void* const* d_in, const int* in_sizes, int n_in,
                              void* d_out, int out_size, void* d_ws, size_t ws_size,
                              hipStream_t stream) {
    const float* x    = (const float*)d_in[0];   // [16,1024,1024]
    const float* w    = (const float*)d_in[1];   // [3072,1024,2]
    const float* bias = (const float*)d_in[2];   // [3072]
    float* zc = (float*)d_out;                               // c_seq out (holds z pre-scan)
    float* fh = (float*)d_out + (size_t)Mtot * Hsz;          // h_seq out (holds f pre-scan)
    unsigned short* a2 = (unsigned short*)d_ws;              // 64 MB
    unsigned short* wb = a2 + (size_t)Mtot * K2;             // 12.6 MB
    unsigned short* ob = wb + (size_t)Ntot * K2;             // 32 MB (o gate, bf16)
    float* Aw = (float*)(ob + (size_t)Mtot * Hsz);           // 2 MB
    float* Bw = Aw + NCH * Bsz * Hsz;                        // 2 MB

    hipLaunchKernelGGL(prep, dim3(2560), dim3(256), 0, stream, x, a2, w, wb);
    hipLaunchKernelGGL(gemm_gates, dim3(768), dim3(512), 0, stream, a2, wb, bias, zc, fh, ob);
    hipLaunchKernelGGL(scan1, dim3(512), dim3(256), 0, stream, zc, fh, Aw, Bw);
    hipLaunchKernelGGL(scan3, dim3(512), dim3(256), 0, stream, zc, fh, ob, Aw, Bw);
}